// Round 1
// baseline (41.270 us; speedup 1.0000x reference)
//
#include <hip/hip_runtime.h>

#define Bn 1024
#define Pn 128
#define Fn 512
#define Dn 256
#define THETA 1e-7f
#define BP (Bn * Pn)

// ---------------------------------------------------------------------------
// GEMM: C = [x; prototypes] @ fb^T.  Rows < Bn -> xf[r][c]; rows >= Bn ->
// pfT[c][p] (transposed store so the main kernel's per-f p-reads coalesce).
// 64x64 tile, K-chunk 64, LDS staged transposed ([k][r]) for float4 reads.
// ---------------------------------------------------------------------------
__global__ __launch_bounds__(256)
void gemm_feat(const float* __restrict__ x, const float* __restrict__ prot,
               const float* __restrict__ fb, float* __restrict__ xf,
               float* __restrict__ pfT)
{
    __shared__ float As[64][68];   // [k][r], pad to 68 floats (16B-aligned rows)
    __shared__ float Fs[64][68];   // [k][c]
    const int tid = threadIdx.x;
    const int rb  = blockIdx.y * 64;   // stacked-row base (0..1151)
    const int cb  = blockIdx.x * 64;   // feature-col base (0..511)
    const int tx  = tid & 15;
    const int ty  = tid >> 4;
    const int lr  = tid >> 2;          // staging row 0..63
    const int lk  = tid & 3;           // staging k4 phase 0..3

    float acc[4][4] = {};

    for (int k0 = 0; k0 < Dn; k0 += 64) {
        #pragma unroll
        for (int q = 0; q < 4; ++q) {
            const int kk = lk + q * 4;                 // k4 index 0..15
            const int r  = rb + lr;
            const float* asrc = (r < Bn) ? (x + (size_t)r * Dn)
                                         : (prot + (size_t)(r - Bn) * Dn);
            float4 av = *(const float4*)(asrc + k0 + kk * 4);
            float4 fv = *(const float4*)(fb + (size_t)(cb + lr) * Dn + k0 + kk * 4);
            As[kk*4+0][lr] = av.x; As[kk*4+1][lr] = av.y;
            As[kk*4+2][lr] = av.z; As[kk*4+3][lr] = av.w;
            Fs[kk*4+0][lr] = fv.x; Fs[kk*4+1][lr] = fv.y;
            Fs[kk*4+2][lr] = fv.z; Fs[kk*4+3][lr] = fv.w;
        }
        __syncthreads();
        #pragma unroll 8
        for (int k = 0; k < 64; ++k) {
            float4 a = *(const float4*)&As[k][ty * 4];
            float4 f = *(const float4*)&Fs[k][tx * 4];
            const float aa[4] = {a.x, a.y, a.z, a.w};
            const float ff[4] = {f.x, f.y, f.z, f.w};
            #pragma unroll
            for (int i = 0; i < 4; ++i)
                #pragma unroll
                for (int j = 0; j < 4; ++j)
                    acc[i][j] = fmaf(aa[i], ff[j], acc[i][j]);
        }
        __syncthreads();
    }

    #pragma unroll
    for (int i = 0; i < 4; ++i) {
        const int r = rb + ty * 4 + i;
        #pragma unroll
        for (int j = 0; j < 4; ++j) {
            const int c = cb + tx * 4 + j;
            if (r < Bn) xf[(size_t)r * Fn + c] = acc[i][j];
            else        pfT[(size_t)c * Pn + (r - Bn)] = acc[i][j];
        }
    }
}

// ---------------------------------------------------------------------------
// Main fused Tversky reduction over an F-chunk.
// Identities (rx=relu(xv), rp=relu(pv), bx=1[xv>0], bp=1[pv>0]):
//   inter      = sum rx*rp
//   M          = sum min(rx,rp)          (auto-masked: 0 unless both>0)
//   SXB        = sum rx*bp,  SPB = sum rp*bx
//   x_minus_p  = SXB - M,    p_minus_x = SPB - M      (exact)
// Each thread: 2 b-rows x 4 p-cols, 4 accumulator types -> 32 f32 regs.
// Block tile: 64 b x 32 p. Grid: (B/64, P/32, S) with F-chunk = F/S.
// ---------------------------------------------------------------------------
__global__ __launch_bounds__(256)
void tversky_main(const float* __restrict__ xf, const float* __restrict__ pfT,
                  const float* __restrict__ alpha_p, const float* __restrict__ beta_p,
                  float* __restrict__ partI, float* __restrict__ partW, int S)
{
    const int tid = threadIdx.x;
    const int tx  = tid & 7;                 // 8 groups of 4 p (float4)
    const int ty  = tid >> 3;                // 32 groups of 2 b
    const int p0  = blockIdx.y * 32 + tx * 4;
    const int b0  = blockIdx.x * 64 + ty * 2;
    const int s   = blockIdx.z;
    const int FC  = Fn / S;
    const int f0  = s * FC;

    float aI[2][4] = {};
    float aM[2][4] = {};
    float aX[2][4] = {};
    float aP[2][4] = {};

    for (int f = f0; f < f0 + FC; f += 4) {
        float4 pr[4];
        #pragma unroll
        for (int j = 0; j < 4; ++j)
            pr[j] = *(const float4*)(pfT + (size_t)(f + j) * Pn + p0);
        float4 xr[2];
        #pragma unroll
        for (int i = 0; i < 2; ++i)
            xr[i] = *(const float4*)(xf + (size_t)(b0 + i) * Fn + f);

        #pragma unroll
        for (int j = 0; j < 4; ++j) {
            const float pv[4] = {pr[j].x, pr[j].y, pr[j].z, pr[j].w};
            float rp[4], bp[4];
            #pragma unroll
            for (int q = 0; q < 4; ++q) {
                rp[q] = fmaxf(pv[q], 0.f);
                bp[q] = (pv[q] > 0.f) ? 1.f : 0.f;
            }
            #pragma unroll
            for (int i = 0; i < 2; ++i) {
                const float* xcomp = (const float*)&xr[i];
                const float xv = xcomp[j];
                const float rx = fmaxf(xv, 0.f);
                const float bx = (xv > 0.f) ? 1.f : 0.f;
                #pragma unroll
                for (int q = 0; q < 4; ++q) {
                    aI[i][q]  = fmaf(rx, rp[q], aI[i][q]);
                    aM[i][q] += fminf(rx, rp[q]);
                    aX[i][q]  = fmaf(rx, bp[q], aX[i][q]);
                    aP[i][q]  = fmaf(rp[q], bx, aP[i][q]);
                }
            }
        }
    }

    const float alpha = *alpha_p;
    const float beta  = *beta_p;
    #pragma unroll
    for (int i = 0; i < 2; ++i) {
        #pragma unroll
        for (int q = 0; q < 4; ++q) {
            const size_t idx = (size_t)s * BP + (size_t)(b0 + i) * Pn + (p0 + q);
            partI[idx] = aI[i][q];
            partW[idx] = alpha * (aX[i][q] - aM[i][q])
                       + beta  * (aP[i][q] - aM[i][q]);
        }
    }
}

// ---------------------------------------------------------------------------
// Epilogue: reduce S partials, compute ratio.
// ---------------------------------------------------------------------------
__global__ __launch_bounds__(256)
void tversky_epi(const float* __restrict__ partI, const float* __restrict__ partW,
                 float* __restrict__ out, int S)
{
    const int idx = blockIdx.x * 256 + threadIdx.x;
    float I = 0.f, W = 0.f;
    for (int s = 0; s < S; ++s) {
        I += partI[(size_t)s * BP + idx];
        W += partW[(size_t)s * BP + idx];
    }
    out[idx] = I / (I + W + THETA);
}

extern "C" void kernel_launch(void* const* d_in, const int* in_sizes, int n_in,
                              void* d_out, int out_size, void* d_ws, size_t ws_size,
                              hipStream_t stream)
{
    const float* x     = (const float*)d_in[0];
    const float* prot  = (const float*)d_in[1];
    const float* fb    = (const float*)d_in[2];
    const float* alpha = (const float*)d_in[3];
    const float* beta  = (const float*)d_in[4];
    float* out = (float*)d_out;

    float* xf  = (float*)d_ws;                 // B*F f32
    float* pfT = xf + (size_t)Bn * Fn;         // F*P f32

    // Pick F-split S by workspace capacity (partials need 2*S*BP f32).
    const size_t base_f = (size_t)Bn * Fn + (size_t)Fn * Pn;
    int S = 8;
    while (S > 1 && (base_f + (size_t)2 * S * BP) * sizeof(float) > ws_size) S >>= 1;

    float* partI = pfT + (size_t)Fn * Pn;
    float* partW = partI + (size_t)S * BP;

    dim3 gb(Fn / 64, (Bn + Pn) / 64);          // 8 x 18 = 144 blocks
    gemm_feat<<<gb, 256, 0, stream>>>(x, prot, fb, xf, pfT);

    dim3 gm(Bn / 64, Pn / 32, S);              // 16 x 4 x S blocks
    tversky_main<<<gm, 256, 0, stream>>>(xf, pfT, alpha, beta, partI, partW, S);

    tversky_epi<<<BP / 256, 256, 0, stream>>>(partI, partW, out, S);
}